// Round 12
// baseline (223.739 us; speedup 1.0000x reference)
//
#include <hip/hip_runtime.h>

#define NLVL 16
#define LOGT 19
#define TMASK ((1u << LOGT) - 1u)
#define SCALE 4096.0f
#define INV_SCALE (1.0f / 4096.0f)
#define NFRAG 22
#define NBINS 4096           // 16^3 Morton buckets (~64 pts = 1 wave per bucket)

typedef _Float16 half_t;
typedef half_t half8 __attribute__((ext_vector_type(8)));
typedef half_t half4 __attribute__((ext_vector_type(4)));
typedef half_t half2v __attribute__((ext_vector_type(2)));
typedef float  float4v __attribute__((ext_vector_type(4)));

__device__ __constant__ float RES_C[NLVL] = {16.f, 20.f, 25.f, 32.f, 40.f, 50.f, 64.f, 80.f,
                                             101.f, 128.f, 161.f, 203.f, 256.f, 322.f, 406.f, 512.f};

__device__ __forceinline__ float4v mfma16(half8 a, half8 b, float4v c) {
    return __builtin_amdgcn_mfma_f32_16x16x32_f16(a, b, c, 0, 0, 0);
}

__device__ __forceinline__ unsigned spread4(unsigned x) {
    x &= 15u;
    x = (x | (x << 4)) & 0x0C3u;
    x = (x | (x << 2)) & 0x249u;
    return x;
}
__device__ __forceinline__ unsigned bin3(float cx, float cy, float cz) {
    const unsigned bx = min(15u, (unsigned)(cx * 16.f));
    const unsigned by = min(15u, (unsigned)(cy * 16.f));
    const unsigned bz = min(15u, (unsigned)(cz * 16.f));
    return spread4(bx) | (spread4(by) << 1) | (spread4(bz) << 2);
}

// ---------------- Kernel P: weight -> fp16 A-frag prepass ----------------
__global__ __launch_bounds__(64, 1) void nerf_wprep(
    const float* __restrict__ w_in, const float* __restrict__ w_h0,
    const float* __restrict__ w_h1, const float* __restrict__ w_out,
    half8* __restrict__ frags)
{
    const int frag = blockIdx.x;
    const int lane = threadIdx.x;
    const int m    = lane & 15;
    const int quad = lane >> 4;

    const float* W; int ncol, row, col;
    if (frag < 4)       { W = w_in;  ncol = 32; row = frag * 16 + m;            col = quad * 8; }
    else if (frag < 12) { const int f = frag - 4;
                          W = w_h0;  ncol = 64; row = (f >> 1) * 16 + m;        col = (f & 1) * 32 + quad * 8; }
    else if (frag < 20) { const int f = frag - 12;
                          W = w_h1;  ncol = 64; row = (f >> 1) * 16 + m;        col = (f & 1) * 32 + quad * 8; }
    else                { const int f = frag - 20;
                          W = w_out; ncol = 64; row = m;                        col = f * 32 + quad * 8; }

    const float* p = W + row * ncol + col;
    half8 r;
    #pragma unroll
    for (int j = 0; j < 8; ++j) r[j] = (half_t)p[j];
    frags[frag * 64 + lane] = r;
}

// ---------------- Sort kernels: Morton-bucket counting sort ----------------
__global__ __launch_bounds__(256, 8) void nerf_hist(
    const float* __restrict__ coords, unsigned* __restrict__ hist, int npts)
{
    const int p = blockIdx.x * 256 + threadIdx.x;
    if (p >= npts) return;
    const unsigned b = bin3(coords[p * 3 + 0], coords[p * 3 + 1], coords[p * 3 + 2]);
    atomicAdd(&hist[b], 1u);
}

__global__ __launch_bounds__(256, 1) void nerf_scan(
    const unsigned* __restrict__ hist, unsigned* __restrict__ offs)
{
    __shared__ unsigned part[256];
    const int t = threadIdx.x;
    unsigned c[NBINS / 256];
    unsigned s = 0;
    #pragma unroll
    for (int i = 0; i < NBINS / 256; ++i) { c[i] = hist[t * (NBINS / 256) + i]; s += c[i]; }
    part[t] = s;
    __syncthreads();
    for (int off = 1; off < 256; off <<= 1) {
        const unsigned v = (t >= off) ? part[t - off] : 0u;
        __syncthreads();
        part[t] += v;
        __syncthreads();
    }
    unsigned run = part[t] - s;           // exclusive prefix of this chunk
    #pragma unroll
    for (int i = 0; i < NBINS / 256; ++i) {
        offs[t * (NBINS / 256) + i] = run;
        run += c[i];
    }
}

__global__ __launch_bounds__(256, 8) void nerf_scatter(
    const float* __restrict__ coords, unsigned* __restrict__ offs,
    int* __restrict__ perm, float* __restrict__ sc, int npts)
{
    const int p = blockIdx.x * 256 + threadIdx.x;
    if (p >= npts) return;
    const float cx = coords[p * 3 + 0];
    const float cy = coords[p * 3 + 1];
    const float cz = coords[p * 3 + 2];
    const unsigned b = bin3(cx, cy, cz);
    const unsigned pos = atomicAdd(&offs[b], 1u);
    perm[pos] = p;
    sc[pos * 3 + 0] = cx;
    sc[pos * 3 + 1] = cy;
    sc[pos * 3 + 2] = cz;
}

// ---------------- Kernel A: XCD-pinned (balanced), spatially-sorted encode ----------------
// XCD k <- level k (first half of grid), then level 15-k (second half): each XCD gets
// exactly one expensive fine level, so per-XCD cost is flat. Morton-sorted points make
// coarse-level gathers L1 hits; fine levels carry the L2 request load.
__global__ __launch_bounds__(256, 8) void nerf_encode_sort(
    const float* __restrict__ sc,
    const float2* __restrict__ tab,
    half_t* __restrict__ encT, int npts)
{
    const int b     = blockIdx.x;
    const int halfg = (int)(gridDim.x >> 1);
    const int hi    = (b >= halfg) ? 1 : 0;
    const int bb    = hi ? (b - halfg) : b;
    const int l     = hi ? (15 - (bb & 7)) : (bb & 7);
    const int pb    = bb >> 3;

    const int side = threadIdx.x & 1;                 // 0 = floor-x, 1 = ceil-x
    const int p0   = pb * 256 + ((threadIdx.x >> 1) << 1);
    const int p1   = p0 + 1;

    const float r = RES_C[l];
    const float2* __restrict__ bp = tab + (((unsigned)l) << LOGT);

    const float ax = sc[p0 * 3 + 0] * r, ay = sc[p0 * 3 + 1] * r, az = sc[p0 * 3 + 2] * r;
    const float afx = floorf(ax), afy = floorf(ay), afz = floorf(az);
    const float agx = ceilf(ax),  agy = ceilf(ay),  agz = ceilf(az);
    const unsigned ahx = side ? (unsigned)(int)agx : (unsigned)(int)afx;
    const float    awx = side ? (ax - afx) : (agx - ax);
    const unsigned ahfy = (unsigned)(int)afy * 2654435761u;
    const unsigned ahgy = (unsigned)(int)agy * 2654435761u;
    const unsigned ahfz = (unsigned)(int)afz * 805459861u;
    const unsigned ahgz = (unsigned)(int)agz * 805459861u;
    const float aty = ay - afy, atz = az - afz, auy = agy - ay, auz = agz - az;

    const float bx = sc[p1 * 3 + 0] * r, by = sc[p1 * 3 + 1] * r, bz = sc[p1 * 3 + 2] * r;
    const float bfx = floorf(bx), bfy = floorf(by), bfz = floorf(bz);
    const float bgx = ceilf(bx),  bgy = ceilf(by),  bgz = ceilf(bz);
    const unsigned bhx = side ? (unsigned)(int)bgx : (unsigned)(int)bfx;
    const float    bwx = side ? (bx - bfx) : (bgx - bx);
    const unsigned bhfy = (unsigned)(int)bfy * 2654435761u;
    const unsigned bhgy = (unsigned)(int)bgy * 2654435761u;
    const unsigned bhfz = (unsigned)(int)bfz * 805459861u;
    const unsigned bhgz = (unsigned)(int)bgz * 805459861u;
    const float bty = by - bfy, btz = bz - bfz, buy = bgy - by, buz = bgz - bz;

    const float2 a0 = bp[(ahx ^ ahfy ^ ahfz) & TMASK];
    const float2 a1 = bp[(ahx ^ ahfy ^ ahgz) & TMASK];
    const float2 a2 = bp[(ahx ^ ahgy ^ ahfz) & TMASK];
    const float2 a3 = bp[(ahx ^ ahgy ^ ahgz) & TMASK];
    const float2 b0 = bp[(bhx ^ bhfy ^ bhfz) & TMASK];
    const float2 b1 = bp[(bhx ^ bhfy ^ bhgz) & TMASK];
    const float2 b2 = bp[(bhx ^ bhgy ^ bhfz) & TMASK];
    const float2 b3 = bp[(bhx ^ bhgy ^ bhgz) & TMASK];

    const float aw0 = awx * auy * auz, aw1 = awx * auy * atz;
    const float aw2 = awx * aty * auz, aw3 = awx * aty * atz;
    const float bw0 = bwx * buy * buz, bw1 = bwx * buy * btz;
    const float bw2 = bwx * bty * buz, bw3 = bwx * bty * btz;

    float ae0 = aw0 * a0.x + aw1 * a1.x + aw2 * a2.x + aw3 * a3.x;
    float ae1 = aw0 * a0.y + aw1 * a1.y + aw2 * a2.y + aw3 * a3.y;
    float be0 = bw0 * b0.x + bw1 * b1.x + bw2 * b2.x + bw3 * b3.x;
    float be1 = bw0 * b0.y + bw1 * b1.y + bw2 * b2.y + bw3 * b3.y;

    ae0 += __shfl_xor(ae0, 1, 64);
    ae1 += __shfl_xor(ae1, 1, 64);
    be0 += __shfl_xor(be0, 1, 64);
    be1 += __shfl_xor(be1, 1, 64);

    if (side == 0) {
        half4 hv;
        hv[0] = (half_t)(ae0 * SCALE); hv[1] = (half_t)(ae1 * SCALE);
        hv[2] = (half_t)(be0 * SCALE); hv[3] = (half_t)(be1 * SCALE);
        *reinterpret_cast<half4*>(&encT[((size_t)l * npts + p0) * 2]) = hv;
    }
}

// ---------------- Kernel B: MFMA MLP, sorted input, scatter output via perm ----------------
__global__ __launch_bounds__(256, 2) void nerf_mlp4(
    const half_t* __restrict__ encT,
    const half8* __restrict__ frags,
    const int* __restrict__ perm,
    const float* __restrict__ b_in, const float* __restrict__ b_h0,
    const float* __restrict__ b_h1, const float* __restrict__ b_out,
    float* __restrict__ out, int npts)
{
    __shared__ half_t actS[4][64 * 64];   // 32 KB

    const int t    = threadIdx.x;
    const int lane = t & 63;
    const int wv   = t >> 6;
    const int m    = lane & 15;
    const int quad = lane >> 4;

    const size_t pbase = (size_t)blockIdx.x * 256 + (size_t)wv * 64;

    half8 be[4];
    #pragma unroll
    for (int T = 0; T < 4; ++T) {
        #pragma unroll
        for (int d = 0; d < 4; ++d) {
            const int L = quad * 4 + d;
            const half2v v = *reinterpret_cast<const half2v*>(
                &encT[((size_t)L * npts + pbase + T * 16 + m) * 2]);
            be[T][d * 2 + 0] = v[0];
            be[T][d * 2 + 1] = v[1];
        }
    }

    int pid[4];
    #pragma unroll
    for (int T = 0; T < 4; ++T) pid[T] = perm[pbase + T * 16 + m];

    half8 aL1[4], aL2[8], aL3[8], aL4[2];
    #pragma unroll
    for (int f = 0; f < 4; ++f) aL1[f] = frags[(0 + f) * 64 + lane];
    #pragma unroll
    for (int f = 0; f < 8; ++f) aL2[f] = frags[(4 + f) * 64 + lane];
    #pragma unroll
    for (int f = 0; f < 8; ++f) aL3[f] = frags[(12 + f) * 64 + lane];
    #pragma unroll
    for (int f = 0; f < 2; ++f) aL4[f] = frags[(20 + f) * 64 + lane];

    float4v bL1[4], bL2[4], bL3[4], bL4;
    #pragma unroll
    for (int mt = 0; mt < 4; ++mt) {
        bL1[mt] = *reinterpret_cast<const float4v*>(b_in + mt * 16 + quad * 4);
        bL2[mt] = *reinterpret_cast<const float4v*>(b_h0 + mt * 16 + quad * 4);
        bL3[mt] = *reinterpret_cast<const float4v*>(b_h1 + mt * 16 + quad * 4);
    }
    bL4 = *reinterpret_cast<const float4v*>(b_out + quad * 4);

    half_t* const buf = &actS[wv][0];
    const float4v zero = {0.f, 0.f, 0.f, 0.f};

    auto storeTile = [&](int lp, int mt, float4v acc, float4v bias) {
        half4 h4;
        #pragma unroll
        for (int r = 0; r < 4; ++r)
            h4[r] = (half_t)fmaxf(fmaf(bias[r], SCALE, acc[r]), 0.f);
        const int c16  = mt * 2 + (quad >> 1);
        const int phys = c16 ^ (lp & 7);
        *reinterpret_cast<half4*>(&buf[lp * 64 + phys * 8 + (quad & 1) * 4]) = h4;
    };
    auto loadB = [&](int lp, int h) -> half8 {
        const int phys = (h * 4 + quad) ^ (lp & 7);
        return *reinterpret_cast<const half8*>(&buf[lp * 64 + phys * 8]);
    };

    #pragma unroll
    for (int T = 0; T < 4; ++T) {
        const int lp = T * 16 + m;
        #pragma unroll
        for (int mt = 0; mt < 4; ++mt) {
            float4v acc = mfma16(aL1[mt], be[T], zero);
            storeTile(lp, mt, acc, bL1[mt]);
        }
    }
    #pragma unroll
    for (int T = 0; T < 4; ++T) {
        const int lp = T * 16 + m;
        const half8 p0 = loadB(lp, 0);
        const half8 p1 = loadB(lp, 1);
        #pragma unroll
        for (int mt = 0; mt < 4; ++mt) {
            float4v acc = mfma16(aL2[mt * 2 + 0], p0, zero);
            acc         = mfma16(aL2[mt * 2 + 1], p1, acc);
            storeTile(lp, mt, acc, bL2[mt]);
        }
    }
    #pragma unroll
    for (int T = 0; T < 4; ++T) {
        const int lp = T * 16 + m;
        const half8 p0 = loadB(lp, 0);
        const half8 p1 = loadB(lp, 1);
        #pragma unroll
        for (int mt = 0; mt < 4; ++mt) {
            float4v acc = mfma16(aL3[mt * 2 + 0], p0, zero);
            acc         = mfma16(aL3[mt * 2 + 1], p1, acc);
            storeTile(lp, mt, acc, bL3[mt]);
        }
    }
    #pragma unroll
    for (int T = 0; T < 4; ++T) {
        const int lp = T * 16 + m;
        const half8 p0 = loadB(lp, 0);
        const half8 p1 = loadB(lp, 1);
        float4v acc = mfma16(aL4[0], p0, zero);
        acc         = mfma16(aL4[1], p1, acc);
        float4v res;
        #pragma unroll
        for (int r = 0; r < 4; ++r)
            res[r] = fmaf(acc[r], INV_SCALE, bL4[r]);
        *reinterpret_cast<float4v*>(out + (size_t)pid[T] * 16 + quad * 4) = res;
    }
}

// ---------------- Fallback: fused kernel (used only if ws too small) ----------------
__global__ __launch_bounds__(256, 2) void nerf_fused(
    const float* __restrict__ coords,
    const float2* __restrict__ tab,
    const float* __restrict__ w_in, const float* __restrict__ b_in,
    const float* __restrict__ w_h0, const float* __restrict__ b_h0,
    const float* __restrict__ w_h1, const float* __restrict__ b_h1,
    const float* __restrict__ w_out, const float* __restrict__ b_out,
    float* __restrict__ out, int npts)
{
    __shared__ half_t encS[256 * 40];
    __shared__ half_t actS[4][2][32 * 64];

    const int t    = threadIdx.x;
    const int lane = t & 63;
    const int wv   = t >> 6;
    const int m    = lane & 15;
    const int quad = lane >> 4;
    const int pt = blockIdx.x * 256 + t;

    {
        const float cx = coords[pt * 3 + 0];
        const float cy = coords[pt * 3 + 1];
        const float cz = coords[pt * 3 + 2];
        float enc[32];
        #pragma unroll
        for (int l = 0; l < NLVL; ++l) {
            const float r = RES_C[l];
            const float sx = cx * r, sy = cy * r, sz = cz * r;
            const float fx = floorf(sx), fy = floorf(sy), fz = floorf(sz);
            const float gx = ceilf(sx),  gy = ceilf(sy),  gz = ceilf(sz);
            const unsigned hfx = (unsigned)(int)fx;
            const unsigned hgx = (unsigned)(int)gx;
            const unsigned hfy = (unsigned)(int)fy * 2654435761u;
            const unsigned hgy = (unsigned)(int)gy * 2654435761u;
            const unsigned hfz = (unsigned)(int)fz * 805459861u;
            const unsigned hgz = (unsigned)(int)gz * 805459861u;
            const float tx = sx - fx, ty = sy - fy, tz = sz - fz;
            const float ux = gx - sx, uy = gy - sy, uz = gz - sz;
            const unsigned lbase = ((unsigned)l) << LOGT;
            float e0 = 0.f, e1 = 0.f;
            #pragma unroll
            for (int o = 0; o < 8; ++o) {
                const unsigned h = ((o & 4) ? hgx : hfx)
                                 ^ ((o & 2) ? hgy : hfy)
                                 ^ ((o & 1) ? hgz : hfz);
                const unsigned idx = h & TMASK;
                const float w = (((o & 4) ? tx : ux)
                              *  ((o & 2) ? ty : uy))
                              *  ((o & 1) ? tz : uz);
                const float2 fv = tab[lbase + idx];
                e0 = fmaf(w, fv.x, e0);
                e1 = fmaf(w, fv.y, e1);
            }
            enc[2 * l + 0] = e0;
            enc[2 * l + 1] = e1;
        }
        #pragma unroll
        for (int c = 0; c < 4; ++c) {
            half8 h8;
            #pragma unroll
            for (int j = 0; j < 8; ++j) h8[j] = (half_t)(enc[c * 8 + j] * SCALE);
            *reinterpret_cast<half8*>(&encS[t * 40 + c * 8]) = h8;
        }
    }

    auto loadA = [&](const float* __restrict__ W, int ncol, int row, int col) -> half8 {
        const float* p = W + row * ncol + col;
        const float4v lo = *reinterpret_cast<const float4v*>(p);
        const float4v hi = *reinterpret_cast<const float4v*>(p + 4);
        half8 r;
        r[0] = (half_t)lo[0]; r[1] = (half_t)lo[1]; r[2] = (half_t)lo[2]; r[3] = (half_t)lo[3];
        r[4] = (half_t)hi[0]; r[5] = (half_t)hi[1]; r[6] = (half_t)hi[2]; r[7] = (half_t)hi[3];
        return r;
    };

    half8 aL1[4], aL2[8], aL3[8], aL4[2];
    #pragma unroll
    for (int mt = 0; mt < 4; ++mt) aL1[mt] = loadA(w_in, 32, mt * 16 + m, quad * 8);
    #pragma unroll
    for (int mt = 0; mt < 4; ++mt) {
        aL2[mt * 2 + 0] = loadA(w_h0, 64, mt * 16 + m, 0 * 32 + quad * 8);
        aL2[mt * 2 + 1] = loadA(w_h0, 64, mt * 16 + m, 1 * 32 + quad * 8);
        aL3[mt * 2 + 0] = loadA(w_h1, 64, mt * 16 + m, 0 * 32 + quad * 8);
        aL3[mt * 2 + 1] = loadA(w_h1, 64, mt * 16 + m, 1 * 32 + quad * 8);
    }
    aL4[0] = loadA(w_out, 64, m, 0 * 32 + quad * 8);
    aL4[1] = loadA(w_out, 64, m, 1 * 32 + quad * 8);

    float4v bL1[4], bL2[4], bL3[4], bL4;
    #pragma unroll
    for (int mt = 0; mt < 4; ++mt) {
        bL1[mt] = *reinterpret_cast<const float4v*>(b_in + mt * 16 + quad * 4);
        bL2[mt] = *reinterpret_cast<const float4v*>(b_h0 + mt * 16 + quad * 4);
        bL3[mt] = *reinterpret_cast<const float4v*>(b_h1 + mt * 16 + quad * 4);
    }
    bL4 = *reinterpret_cast<const float4v*>(b_out + quad * 4);

    half_t* const ping = &actS[wv][0][0];
    half_t* const pong = &actS[wv][1][0];
    const float4v zero = {0.f, 0.f, 0.f, 0.f};

    auto storeTile = [&](half_t* buf, int lp, int mt, float4v acc, float4v bias) {
        half4 h4;
        #pragma unroll
        for (int r = 0; r < 4; ++r)
            h4[r] = (half_t)fmaxf(fmaf(bias[r], SCALE, acc[r]), 0.f);
        const int c16  = mt * 2 + (quad >> 1);
        const int phys = c16 ^ (lp & 7);
        *reinterpret_cast<half4*>(&buf[lp * 64 + phys * 8 + (quad & 1) * 4]) = h4;
    };
    auto loadB = [&](half_t* buf, int lp, int h) -> half8 {
        const int phys = (h * 4 + quad) ^ (lp & 7);
        return *reinterpret_cast<const half8*>(&buf[lp * 64 + phys * 8]);
    };

    for (int g = 0; g < 2; ++g) {
        #pragma unroll
        for (int nt = 0; nt < 2; ++nt) {
            const int lp   = nt * 16 + m;
            const int prow = wv * 64 + g * 32 + lp;
            const half8 bfr = *reinterpret_cast<const half8*>(&encS[prow * 40 + quad * 8]);
            #pragma unroll
            for (int mt = 0; mt < 4; ++mt) {
                float4v acc = mfma16(aL1[mt], bfr, zero);
                storeTile(ping, lp, mt, acc, bL1[mt]);
            }
            {
                const half8 p0 = loadB(ping, lp, 0);
                const half8 p1 = loadB(ping, lp, 1);
                #pragma unroll
                for (int mt = 0; mt < 4; ++mt) {
                    float4v acc = mfma16(aL2[mt * 2 + 0], p0, zero);
                    acc         = mfma16(aL2[mt * 2 + 1], p1, acc);
                    storeTile(pong, lp, mt, acc, bL2[mt]);
                }
            }
            {
                const half8 p0 = loadB(pong, lp, 0);
                const half8 p1 = loadB(pong, lp, 1);
                #pragma unroll
                for (int mt = 0; mt < 4; ++mt) {
                    float4v acc = mfma16(aL3[mt * 2 + 0], p0, zero);
                    acc         = mfma16(aL3[mt * 2 + 1], p1, acc);
                    storeTile(ping, lp, mt, acc, bL3[mt]);
                }
            }
            {
                const half8 p0 = loadB(ping, lp, 0);
                const half8 p1 = loadB(ping, lp, 1);
                float4v acc = mfma16(aL4[0], p0, zero);
                acc         = mfma16(aL4[1], p1, acc);
                float4v res;
                #pragma unroll
                for (int r = 0; r < 4; ++r)
                    res[r] = fmaf(acc[r], INV_SCALE, bL4[r]);
                const size_t ptg = (size_t)blockIdx.x * 256 + (size_t)wv * 64 + g * 32 + lp;
                *reinterpret_cast<float4v*>(out + ptg * 16 + quad * 4) = res;
            }
        }
    }
}

extern "C" void kernel_launch(void* const* d_in, const int* in_sizes, int n_in,
                              void* d_out, int out_size, void* d_ws, size_t ws_size,
                              hipStream_t stream) {
    const float*  coords = (const float*)d_in[0];
    const float2* tables = (const float2*)d_in[1];
    const float*  w_in   = (const float*)d_in[2];
    const float*  b_in   = (const float*)d_in[3];
    const float*  w_h0   = (const float*)d_in[4];
    const float*  b_h0   = (const float*)d_in[5];
    const float*  w_h1   = (const float*)d_in[6];
    const float*  b_h1   = (const float*)d_in[7];
    const float*  w_out  = (const float*)d_in[8];
    const float*  b_out  = (const float*)d_in[9];
    float* out = (float*)d_out;

    const int npts = in_sizes[0] / 3;      // 262144
    const size_t encBytes  = (size_t)npts * 32 * sizeof(half_t);   // 16.8 MB
    const size_t fragBytes = (size_t)NFRAG * 64 * sizeof(half8);   // 22.5 KB
    const size_t histBytes = (size_t)NBINS * 4;                    // 16 KB
    const size_t offBytes  = (size_t)NBINS * 4;                    // 16 KB
    const size_t permBytes = (size_t)npts * 4;                     // 1 MB
    const size_t scBytes   = (size_t)npts * 12;                    // 3 MB
    const size_t need = encBytes + fragBytes + histBytes + offBytes + permBytes + scBytes;

    if (ws_size >= need && (npts & 255) == 0) {
        char* w = (char*)d_ws;
        half_t*   encT  = (half_t*)w;    w += encBytes;
        half8*    frags = (half8*)w;     w += fragBytes;
        unsigned* hist  = (unsigned*)w;  w += histBytes;
        unsigned* offs  = (unsigned*)w;  w += offBytes;
        int*      perm  = (int*)w;       w += permBytes;
        float*    sc    = (float*)w;

        hipMemsetAsync(hist, 0, histBytes, stream);
        nerf_wprep<<<NFRAG, 64, 0, stream>>>(w_in, w_h0, w_h1, w_out, frags);
        nerf_hist<<<npts / 256, 256, 0, stream>>>(coords, hist, npts);
        nerf_scan<<<1, 256, 0, stream>>>(hist, offs);
        nerf_scatter<<<npts / 256, 256, 0, stream>>>(coords, offs, perm, sc, npts);
        nerf_encode_sort<<<(npts >> 8) * NLVL, 256, 0, stream>>>(sc, tables, encT, npts);
        nerf_mlp4<<<npts / 256, 256, 0, stream>>>(encT, frags, perm,
                                                  b_in, b_h0, b_h1, b_out,
                                                  out, npts);
    } else {
        nerf_fused<<<npts / 256, 256, 0, stream>>>(coords, tables,
                                                   w_in, b_in, w_h0, b_h0,
                                                   w_h1, b_h1, w_out, b_out,
                                                   out, npts);
    }
}

// Round 13
// 197.446 us; speedup vs baseline: 1.1332x; 1.1332x over previous
//
#include <hip/hip_runtime.h>

#define NLVL 16
#define LOGT 19
#define TMASK ((1u << LOGT) - 1u)
#define SCALE 4096.0f
#define INV_SCALE (1.0f / 4096.0f)
#define NFRAG 22

typedef _Float16 half_t;
typedef half_t half8 __attribute__((ext_vector_type(8)));
typedef half_t half4 __attribute__((ext_vector_type(4)));
typedef half_t half2v __attribute__((ext_vector_type(2)));
typedef float  float4v __attribute__((ext_vector_type(4)));

__device__ __constant__ float RES_C[NLVL] = {16.f, 20.f, 25.f, 32.f, 40.f, 50.f, 64.f, 80.f,
                                             101.f, 128.f, 161.f, 203.f, 256.f, 322.f, 406.f, 512.f};

__device__ __forceinline__ float4v mfma16(half8 a, half8 b, float4v c) {
    return __builtin_amdgcn_mfma_f32_16x16x32_f16(a, b, c, 0, 0, 0);
}

// ---------------- Kernel P: weight -> fp16 A-frag prepass ----------------
__global__ __launch_bounds__(64, 1) void nerf_wprep(
    const float* __restrict__ w_in, const float* __restrict__ w_h0,
    const float* __restrict__ w_h1, const float* __restrict__ w_out,
    half8* __restrict__ frags)
{
    const int frag = blockIdx.x;       // 0..21
    const int lane = threadIdx.x;      // 0..63
    const int m    = lane & 15;
    const int quad = lane >> 4;

    const float* W; int ncol, row, col;
    if (frag < 4)       { W = w_in;  ncol = 32; row = frag * 16 + m;            col = quad * 8; }
    else if (frag < 12) { const int f = frag - 4;
                          W = w_h0;  ncol = 64; row = (f >> 1) * 16 + m;        col = (f & 1) * 32 + quad * 8; }
    else if (frag < 20) { const int f = frag - 12;
                          W = w_h1;  ncol = 64; row = (f >> 1) * 16 + m;        col = (f & 1) * 32 + quad * 8; }
    else                { const int f = frag - 20;
                          W = w_out; ncol = 64; row = m;                        col = f * 32 + quad * 8; }

    const float* p = W + row * ncol + col;
    half8 r;
    #pragma unroll
    for (int j = 0; j < 8; ++j) r[j] = (half_t)p[j];
    frags[frag * 64 + lane] = r;
}

// ---------------- Kernel A: XCD-pinned level-major encode (R10 best) ----------------
// Block b -> level (b&7) + 8*(b >= grid/2); with round-robin block->XCD dispatch each
// XCD's 4MB L2 holds exactly its current level's table (FETCH ~= one cold table read).
// Encode sits at the measured L2 request-rate wall (~0.69 line-req/cy/channel):
// 18.9M line-requests -> ~89 us. 2 lanes/pt (floor-x/ceil-x share a 64B line 87.5%,
// TA merges), 2 pts/thread.
__global__ __launch_bounds__(256, 8) void nerf_encode_pin(
    const float* __restrict__ coords,
    const float2* __restrict__ tab,
    half_t* __restrict__ encT, int npts)
{
    const int b    = blockIdx.x;
    const int half = (int)(gridDim.x >> 1);
    const int hi   = (b >= half) ? 1 : 0;
    const int l    = (b & 7) + (hi << 3);
    const int pb   = (hi ? (b - half) : b) >> 3;

    const int side = threadIdx.x & 1;                // 0 = floor-x, 1 = ceil-x
    const int base = pb * 256 + (threadIdx.x >> 1);
    const int p0 = base, p1 = base + 128;

    const float r = RES_C[l];
    const float2* __restrict__ bp = tab + (((unsigned)l) << LOGT);

    const float ax = coords[p0 * 3 + 0] * r, ay = coords[p0 * 3 + 1] * r, az = coords[p0 * 3 + 2] * r;
    const float afx = floorf(ax), afy = floorf(ay), afz = floorf(az);
    const float agx = ceilf(ax),  agy = ceilf(ay),  agz = ceilf(az);
    const unsigned ahx = side ? (unsigned)(int)agx : (unsigned)(int)afx;
    const float    awx = side ? (ax - afx) : (agx - ax);
    const unsigned ahfy = (unsigned)(int)afy * 2654435761u;
    const unsigned ahgy = (unsigned)(int)agy * 2654435761u;
    const unsigned ahfz = (unsigned)(int)afz * 805459861u;
    const unsigned ahgz = (unsigned)(int)agz * 805459861u;
    const float aty = ay - afy, atz = az - afz, auy = agy - ay, auz = agz - az;

    const float bx = coords[p1 * 3 + 0] * r, by = coords[p1 * 3 + 1] * r, bz = coords[p1 * 3 + 2] * r;
    const float bfx = floorf(bx), bfy = floorf(by), bfz = floorf(bz);
    const float bgx = ceilf(bx),  bgy = ceilf(by),  bgz = ceilf(bz);
    const unsigned bhx = side ? (unsigned)(int)bgx : (unsigned)(int)bfx;
    const float    bwx = side ? (bx - bfx) : (bgx - bx);
    const unsigned bhfy = (unsigned)(int)bfy * 2654435761u;
    const unsigned bhgy = (unsigned)(int)bgy * 2654435761u;
    const unsigned bhfz = (unsigned)(int)bfz * 805459861u;
    const unsigned bhgz = (unsigned)(int)bgz * 805459861u;
    const float bty = by - bfy, btz = bz - bfz, buy = bgy - by, buz = bgz - bz;

    const float2 a0 = bp[(ahx ^ ahfy ^ ahfz) & TMASK];
    const float2 a1 = bp[(ahx ^ ahfy ^ ahgz) & TMASK];
    const float2 a2 = bp[(ahx ^ ahgy ^ ahfz) & TMASK];
    const float2 a3 = bp[(ahx ^ ahgy ^ ahgz) & TMASK];
    const float2 b0 = bp[(bhx ^ bhfy ^ bhfz) & TMASK];
    const float2 b1 = bp[(bhx ^ bhfy ^ bhgz) & TMASK];
    const float2 b2 = bp[(bhx ^ bhgy ^ bhfz) & TMASK];
    const float2 b3 = bp[(bhx ^ bhgy ^ bhgz) & TMASK];

    const float aw0 = awx * auy * auz, aw1 = awx * auy * atz;
    const float aw2 = awx * aty * auz, aw3 = awx * aty * atz;
    const float bw0 = bwx * buy * buz, bw1 = bwx * buy * btz;
    const float bw2 = bwx * bty * buz, bw3 = bwx * bty * btz;

    float ae0 = aw0 * a0.x + aw1 * a1.x + aw2 * a2.x + aw3 * a3.x;
    float ae1 = aw0 * a0.y + aw1 * a1.y + aw2 * a2.y + aw3 * a3.y;
    float be0 = bw0 * b0.x + bw1 * b1.x + bw2 * b2.x + bw3 * b3.x;
    float be1 = bw0 * b0.y + bw1 * b1.y + bw2 * b2.y + bw3 * b3.y;

    ae0 += __shfl_xor(ae0, 1, 64);
    ae1 += __shfl_xor(ae1, 1, 64);
    be0 += __shfl_xor(be0, 1, 64);
    be1 += __shfl_xor(be1, 1, 64);

    if (side == 0) {
        half2v h0; h0[0] = (half_t)(ae0 * SCALE); h0[1] = (half_t)(ae1 * SCALE);
        half2v h1; h1[0] = (half_t)(be0 * SCALE); h1[1] = (half_t)(be1 * SCALE);
        *reinterpret_cast<half2v*>(&encT[((size_t)l * npts + p0) * 2]) = h0;
        *reinterpret_cast<half2v*>(&encT[((size_t)l * npts + p1) * 2]) = h1;
    }
}

// ---------------- Kernel B: MFMA MLP, prebuilt A-frags, single 32KB LDS buffer ----------------
// Per-wave slice; same-wave DS ops are in-order, so each layer can read its row fully
// then overwrite it — no ping/pong needed (correctness proven in R11/R12 passes).
__global__ __launch_bounds__(256, 2) void nerf_mlp4(
    const half_t* __restrict__ encT,
    const half8* __restrict__ frags,
    const float* __restrict__ b_in, const float* __restrict__ b_h0,
    const float* __restrict__ b_h1, const float* __restrict__ b_out,
    float* __restrict__ out, int npts)
{
    __shared__ half_t actS[4][64 * 64];   // 32 KB

    const int t    = threadIdx.x;
    const int lane = t & 63;
    const int wv   = t >> 6;
    const int m    = lane & 15;
    const int quad = lane >> 4;

    const size_t pbase = (size_t)blockIdx.x * 256 + (size_t)wv * 64;

    half8 be[4];
    #pragma unroll
    for (int T = 0; T < 4; ++T) {
        #pragma unroll
        for (int d = 0; d < 4; ++d) {
            const int L = quad * 4 + d;
            const half2v v = *reinterpret_cast<const half2v*>(
                &encT[((size_t)L * npts + pbase + T * 16 + m) * 2]);
            be[T][d * 2 + 0] = v[0];
            be[T][d * 2 + 1] = v[1];
        }
    }

    half8 aL1[4], aL2[8], aL3[8], aL4[2];
    #pragma unroll
    for (int f = 0; f < 4; ++f) aL1[f] = frags[(0 + f) * 64 + lane];
    #pragma unroll
    for (int f = 0; f < 8; ++f) aL2[f] = frags[(4 + f) * 64 + lane];
    #pragma unroll
    for (int f = 0; f < 8; ++f) aL3[f] = frags[(12 + f) * 64 + lane];
    #pragma unroll
    for (int f = 0; f < 2; ++f) aL4[f] = frags[(20 + f) * 64 + lane];

    float4v bL1[4], bL2[4], bL3[4], bL4;
    #pragma unroll
    for (int mt = 0; mt < 4; ++mt) {
        bL1[mt] = *reinterpret_cast<const float4v*>(b_in + mt * 16 + quad * 4);
        bL2[mt] = *reinterpret_cast<const float4v*>(b_h0 + mt * 16 + quad * 4);
        bL3[mt] = *reinterpret_cast<const float4v*>(b_h1 + mt * 16 + quad * 4);
    }
    bL4 = *reinterpret_cast<const float4v*>(b_out + quad * 4);

    half_t* const buf = &actS[wv][0];
    const float4v zero = {0.f, 0.f, 0.f, 0.f};

    auto storeTile = [&](int lp, int mt, float4v acc, float4v bias) {
        half4 h4;
        #pragma unroll
        for (int r = 0; r < 4; ++r)
            h4[r] = (half_t)fmaxf(fmaf(bias[r], SCALE, acc[r]), 0.f);
        const int c16  = mt * 2 + (quad >> 1);
        const int phys = c16 ^ (lp & 7);
        *reinterpret_cast<half4*>(&buf[lp * 64 + phys * 8 + (quad & 1) * 4]) = h4;
    };
    auto loadB = [&](int lp, int h) -> half8 {
        const int phys = (h * 4 + quad) ^ (lp & 7);
        return *reinterpret_cast<const half8*>(&buf[lp * 64 + phys * 8]);
    };

    // layer 1
    #pragma unroll
    for (int T = 0; T < 4; ++T) {
        const int lp = T * 16 + m;
        #pragma unroll
        for (int mt = 0; mt < 4; ++mt) {
            float4v acc = mfma16(aL1[mt], be[T], zero);
            storeTile(lp, mt, acc, bL1[mt]);
        }
    }
    // layer 2
    #pragma unroll
    for (int T = 0; T < 4; ++T) {
        const int lp = T * 16 + m;
        const half8 p0 = loadB(lp, 0);
        const half8 p1 = loadB(lp, 1);
        #pragma unroll
        for (int mt = 0; mt < 4; ++mt) {
            float4v acc = mfma16(aL2[mt * 2 + 0], p0, zero);
            acc         = mfma16(aL2[mt * 2 + 1], p1, acc);
            storeTile(lp, mt, acc, bL2[mt]);
        }
    }
    // layer 3
    #pragma unroll
    for (int T = 0; T < 4; ++T) {
        const int lp = T * 16 + m;
        const half8 p0 = loadB(lp, 0);
        const half8 p1 = loadB(lp, 1);
        #pragma unroll
        for (int mt = 0; mt < 4; ++mt) {
            float4v acc = mfma16(aL3[mt * 2 + 0], p0, zero);
            acc         = mfma16(aL3[mt * 2 + 1], p1, acc);
            storeTile(lp, mt, acc, bL3[mt]);
        }
    }
    // layer 4 + coalesced store
    #pragma unroll
    for (int T = 0; T < 4; ++T) {
        const int lp = T * 16 + m;
        const half8 p0 = loadB(lp, 0);
        const half8 p1 = loadB(lp, 1);
        float4v acc = mfma16(aL4[0], p0, zero);
        acc         = mfma16(aL4[1], p1, acc);
        float4v res;
        #pragma unroll
        for (int r = 0; r < 4; ++r)
            res[r] = fmaf(acc[r], INV_SCALE, bL4[r]);
        *reinterpret_cast<float4v*>(out + (pbase + lp) * 16 + quad * 4) = res;
    }
}

// ---------------- Fallback: fused kernel (used only if ws too small) ----------------
__global__ __launch_bounds__(256, 2) void nerf_fused(
    const float* __restrict__ coords,
    const float2* __restrict__ tab,
    const float* __restrict__ w_in, const float* __restrict__ b_in,
    const float* __restrict__ w_h0, const float* __restrict__ b_h0,
    const float* __restrict__ w_h1, const float* __restrict__ b_h1,
    const float* __restrict__ w_out, const float* __restrict__ b_out,
    float* __restrict__ out, int npts)
{
    __shared__ half_t encS[256 * 40];
    __shared__ half_t actS[4][2][32 * 64];

    const int t    = threadIdx.x;
    const int lane = t & 63;
    const int wv   = t >> 6;
    const int m    = lane & 15;
    const int quad = lane >> 4;
    const int pt = blockIdx.x * 256 + t;

    {
        const float cx = coords[pt * 3 + 0];
        const float cy = coords[pt * 3 + 1];
        const float cz = coords[pt * 3 + 2];
        float enc[32];
        #pragma unroll
        for (int l = 0; l < NLVL; ++l) {
            const float r = RES_C[l];
            const float sx = cx * r, sy = cy * r, sz = cz * r;
            const float fx = floorf(sx), fy = floorf(sy), fz = floorf(sz);
            const float gx = ceilf(sx),  gy = ceilf(sy),  gz = ceilf(sz);
            const unsigned hfx = (unsigned)(int)fx;
            const unsigned hgx = (unsigned)(int)gx;
            const unsigned hfy = (unsigned)(int)fy * 2654435761u;
            const unsigned hgy = (unsigned)(int)gy * 2654435761u;
            const unsigned hfz = (unsigned)(int)fz * 805459861u;
            const unsigned hgz = (unsigned)(int)gz * 805459861u;
            const float tx = sx - fx, ty = sy - fy, tz = sz - fz;
            const float ux = gx - sx, uy = gy - sy, uz = gz - sz;
            const unsigned lbase = ((unsigned)l) << LOGT;
            float e0 = 0.f, e1 = 0.f;
            #pragma unroll
            for (int o = 0; o < 8; ++o) {
                const unsigned h = ((o & 4) ? hgx : hfx)
                                 ^ ((o & 2) ? hgy : hfy)
                                 ^ ((o & 1) ? hgz : hfz);
                const unsigned idx = h & TMASK;
                const float w = (((o & 4) ? tx : ux)
                              *  ((o & 2) ? ty : uy))
                              *  ((o & 1) ? tz : uz);
                const float2 fv = tab[lbase + idx];
                e0 = fmaf(w, fv.x, e0);
                e1 = fmaf(w, fv.y, e1);
            }
            enc[2 * l + 0] = e0;
            enc[2 * l + 1] = e1;
        }
        #pragma unroll
        for (int c = 0; c < 4; ++c) {
            half8 h8;
            #pragma unroll
            for (int j = 0; j < 8; ++j) h8[j] = (half_t)(enc[c * 8 + j] * SCALE);
            *reinterpret_cast<half8*>(&encS[t * 40 + c * 8]) = h8;
        }
    }

    auto loadA = [&](const float* __restrict__ W, int ncol, int row, int col) -> half8 {
        const float* p = W + row * ncol + col;
        const float4v lo = *reinterpret_cast<const float4v*>(p);
        const float4v hi = *reinterpret_cast<const float4v*>(p + 4);
        half8 r;
        r[0] = (half_t)lo[0]; r[1] = (half_t)lo[1]; r[2] = (half_t)lo[2]; r[3] = (half_t)lo[3];
        r[4] = (half_t)hi[0]; r[5] = (half_t)hi[1]; r[6] = (half_t)hi[2]; r[7] = (half_t)hi[3];
        return r;
    };

    half8 aL1[4], aL2[8], aL3[8], aL4[2];
    #pragma unroll
    for (int mt = 0; mt < 4; ++mt) aL1[mt] = loadA(w_in, 32, mt * 16 + m, quad * 8);
    #pragma unroll
    for (int mt = 0; mt < 4; ++mt) {
        aL2[mt * 2 + 0] = loadA(w_h0, 64, mt * 16 + m, 0 * 32 + quad * 8);
        aL2[mt * 2 + 1] = loadA(w_h0, 64, mt * 16 + m, 1 * 32 + quad * 8);
        aL3[mt * 2 + 0] = loadA(w_h1, 64, mt * 16 + m, 0 * 32 + quad * 8);
        aL3[mt * 2 + 1] = loadA(w_h1, 64, mt * 16 + m, 1 * 32 + quad * 8);
    }
    aL4[0] = loadA(w_out, 64, m, 0 * 32 + quad * 8);
    aL4[1] = loadA(w_out, 64, m, 1 * 32 + quad * 8);

    float4v bL1[4], bL2[4], bL3[4], bL4;
    #pragma unroll
    for (int mt = 0; mt < 4; ++mt) {
        bL1[mt] = *reinterpret_cast<const float4v*>(b_in + mt * 16 + quad * 4);
        bL2[mt] = *reinterpret_cast<const float4v*>(b_h0 + mt * 16 + quad * 4);
        bL3[mt] = *reinterpret_cast<const float4v*>(b_h1 + mt * 16 + quad * 4);
    }
    bL4 = *reinterpret_cast<const float4v*>(b_out + quad * 4);

    half_t* const ping = &actS[wv][0][0];
    half_t* const pong = &actS[wv][1][0];
    const float4v zero = {0.f, 0.f, 0.f, 0.f};

    auto storeTile = [&](half_t* buf, int lp, int mt, float4v acc, float4v bias) {
        half4 h4;
        #pragma unroll
        for (int r = 0; r < 4; ++r)
            h4[r] = (half_t)fmaxf(fmaf(bias[r], SCALE, acc[r]), 0.f);
        const int c16  = mt * 2 + (quad >> 1);
        const int phys = c16 ^ (lp & 7);
        *reinterpret_cast<half4*>(&buf[lp * 64 + phys * 8 + (quad & 1) * 4]) = h4;
    };
    auto loadB = [&](half_t* buf, int lp, int h) -> half8 {
        const int phys = (h * 4 + quad) ^ (lp & 7);
        return *reinterpret_cast<const half8*>(&buf[lp * 64 + phys * 8]);
    };

    for (int g = 0; g < 2; ++g) {
        #pragma unroll
        for (int nt = 0; nt < 2; ++nt) {
            const int lp   = nt * 16 + m;
            const int prow = wv * 64 + g * 32 + lp;
            const half8 bfr = *reinterpret_cast<const half8*>(&encS[prow * 40 + quad * 8]);
            #pragma unroll
            for (int mt = 0; mt < 4; ++mt) {
                float4v acc = mfma16(aL1[mt], bfr, zero);
                storeTile(ping, lp, mt, acc, bL1[mt]);
            }
            {
                const half8 p0 = loadB(ping, lp, 0);
                const half8 p1 = loadB(ping, lp, 1);
                #pragma unroll
                for (int mt = 0; mt < 4; ++mt) {
                    float4v acc = mfma16(aL2[mt * 2 + 0], p0, zero);
                    acc         = mfma16(aL2[mt * 2 + 1], p1, acc);
                    storeTile(pong, lp, mt, acc, bL2[mt]);
                }
            }
            {
                const half8 p0 = loadB(pong, lp, 0);
                const half8 p1 = loadB(pong, lp, 1);
                #pragma unroll
                for (int mt = 0; mt < 4; ++mt) {
                    float4v acc = mfma16(aL3[mt * 2 + 0], p0, zero);
                    acc         = mfma16(aL3[mt * 2 + 1], p1, acc);
                    storeTile(ping, lp, mt, acc, bL3[mt]);
                }
            }
            {
                const half8 p0 = loadB(ping, lp, 0);
                const half8 p1 = loadB(ping, lp, 1);
                float4v acc = mfma16(aL4[0], p0, zero);
                acc         = mfma16(aL4[1], p1, acc);
                float4v res;
                #pragma unroll
                for (int r = 0; r < 4; ++r)
                    res[r] = fmaf(acc[r], INV_SCALE, bL4[r]);
                const size_t ptg = (size_t)blockIdx.x * 256 + (size_t)wv * 64 + g * 32 + lp;
                *reinterpret_cast<float4v*>(out + ptg * 16 + quad * 4) = res;
            }
        }
    }
}

extern "C" void kernel_launch(void* const* d_in, const int* in_sizes, int n_in,
                              void* d_out, int out_size, void* d_ws, size_t ws_size,
                              hipStream_t stream) {
    const float*  coords = (const float*)d_in[0];
    const float2* tables = (const float2*)d_in[1];
    const float*  w_in   = (const float*)d_in[2];
    const float*  b_in   = (const float*)d_in[3];
    const float*  w_h0   = (const float*)d_in[4];
    const float*  b_h0   = (const float*)d_in[5];
    const float*  w_h1   = (const float*)d_in[6];
    const float*  b_h1   = (const float*)d_in[7];
    const float*  w_out  = (const float*)d_in[8];
    const float*  b_out  = (const float*)d_in[9];
    float* out = (float*)d_out;

    const int npts = in_sizes[0] / 3;      // 262144
    const size_t encBytes  = (size_t)npts * 32 * sizeof(half_t);   // 16.8 MB
    const size_t fragBytes = (size_t)NFRAG * 64 * sizeof(half8);   // 22.5 KB

    if (ws_size >= encBytes + fragBytes && (npts & 255) == 0) {
        half_t* encT  = (half_t*)d_ws;
        half8*  frags = (half8*)((char*)d_ws + encBytes);
        nerf_wprep<<<NFRAG, 64, 0, stream>>>(w_in, w_h0, w_h1, w_out, frags);
        const int bpl = npts >> 8;                         // 1024 blocks per level
        nerf_encode_pin<<<bpl * NLVL, 256, 0, stream>>>(coords, tables, encT, npts);
        nerf_mlp4<<<npts / 256, 256, 0, stream>>>(encT, frags,
                                                  b_in, b_h0, b_h1, b_out,
                                                  out, npts);
    } else {
        nerf_fused<<<npts / 256, 256, 0, stream>>>(coords, tables,
                                                   w_in, b_in, w_h0, b_h0,
                                                   w_h1, b_h1, w_out, b_out,
                                                   out, npts);
    }
}